// Round 1
// 316.499 us; speedup vs baseline: 1.0154x; 1.0154x over previous
//
#include <hip/hip_runtime.h>
#include <stdint.h>

typedef unsigned short u16;
typedef __attribute__((ext_vector_type(8))) short short8;
typedef __attribute__((ext_vector_type(4))) float floatx4;

#define S_LEN 2048
#define NQKV 3072

#if __has_builtin(__builtin_amdgcn_exp2f)
#define EXP2F __builtin_amdgcn_exp2f
#else
#define EXP2F exp2f
#endif

__device__ inline float bf2f(u16 u) {
  union { uint32_t u; float f; } v; v.u = ((uint32_t)u) << 16; return v.f;
}
__device__ inline u16 f2bf(float f) {
  union { float f; uint32_t u; } v; v.f = f;
  uint32_t r = v.u + 0x7fffu + ((v.u >> 16) & 1u);
  return (u16)(r >> 16);
}
__device__ inline void gl2lds16(const u16* g, u16* l) {
  __builtin_amdgcn_global_load_lds((const __attribute__((address_space(1))) uint32_t*)g,
                                   (__attribute__((address_space(3))) uint32_t*)l, 16, 0, 0);
}

// ---------------- cast fp32 -> bf16, 4 elems/thread ----------------
__global__ void cast_k(const float* __restrict__ in, u16* __restrict__ out, int n4) {
  int i = blockIdx.x * 256 + threadIdx.x;
  if (i >= n4) return;
  float4 v = ((const float4*)in)[i];
  ushort4 o;
  o.x = f2bf(v.x); o.y = f2bf(v.y); o.z = f2bf(v.z); o.w = f2bf(v.w);
  ((ushort4*)out)[i] = o;
}

// ---------------- transpose+cast: in fp32 [K][N] -> out bf16 [N][K] ----------------
__global__ void transpose_k(const float* __restrict__ in, u16* __restrict__ out, int K, int N) {
  __shared__ u16 tile[32][33];
  int n0 = blockIdx.x * 32, k0 = blockIdx.y * 32;
  int tx = threadIdx.x, ty = threadIdx.y;  // 32 x 8
#pragma unroll
  for (int i = 0; i < 4; i++)
    tile[ty + 8 * i][tx] = f2bf(in[(size_t)(k0 + ty + 8 * i) * N + n0 + tx]);
  __syncthreads();
#pragma unroll
  for (int i = 0; i < 4; i++)
    out[(size_t)(n0 + ty + 8 * i) * K + k0 + tx] = tile[tx][ty + 8 * i];
}

// ---------------- V transpose: qkv V region [key][d] -> vt [bz][d][key] (bf16) ----------------
__global__ void vtrans_k(const u16* __restrict__ qkv, u16* __restrict__ vt) {
  __shared__ u16 tile[32][33];
  int bk = blockIdx.x * 32, bd = blockIdx.y * 32, bz = blockIdx.z;
  int bb = bz >> 2, kvh = bz & 3;
  const u16* src = qkv + ((size_t)bb * S_LEN) * NQKV + 2560 + kvh * 128;
  u16* dst = vt + (size_t)bz * 128 * 2048;
  int tx = threadIdx.x, ty = threadIdx.y;
#pragma unroll
  for (int i = 0; i < 4; i++)
    tile[ty + 8 * i][tx] = src[(size_t)(bk + ty + 8 * i) * NQKV + bd + tx];
  __syncthreads();
#pragma unroll
  for (int i = 0; i < 4; i++)
    dst[(size_t)(bd + ty + 8 * i) * 2048 + bk + tx] = tile[tx][ty + 8 * i];
}

// ---------------- GEMM: C[M][N] = A[M][K] * Bt[N][K]^T (bf16 in, fp32 acc) ----------------
template <bool OUTF32>
__global__ __launch_bounds__(256) void gemm_bt(const u16* __restrict__ A, const u16* __restrict__ Bt,
                                               void* __restrict__ Cv, int M, int N, int K) {
  __shared__ u16 As[128 * 32];
  __shared__ u16 Bs[128 * 32];
  const int m0 = blockIdx.y * 128, n0 = blockIdx.x * 128;
  const int t = threadIdx.x, w = t >> 6, lane = t & 63;
  const int quad = lane >> 4, l16 = lane & 15;
  const int wm = (w >> 1) * 64, wn = (w & 1) * 64;
  const int lrow = lane >> 2, lk = (lane & 3) * 8;
  floatx4 acc[4][4] = {};
  for (int k0 = 0; k0 < K; k0 += 32) {
#pragma unroll
    for (int c = 2 * w; c <= 2 * w + 1; ++c) {
      int row = c * 16 + lrow;
      gl2lds16(A + (size_t)(m0 + row) * K + k0 + lk, As + c * 512 + lane * 8);
      gl2lds16(Bt + (size_t)(n0 + row) * K + k0 + lk, Bs + c * 512 + lane * 8);
    }
    __syncthreads();
    short8 a[4], b[4];
#pragma unroll
    for (int mt = 0; mt < 4; mt++) a[mt] = *(const short8*)(As + (wm + mt * 16 + l16) * 32 + quad * 8);
#pragma unroll
    for (int nt = 0; nt < 4; nt++) b[nt] = *(const short8*)(Bs + (wn + nt * 16 + l16) * 32 + quad * 8);
#pragma unroll
    for (int mt = 0; mt < 4; mt++)
#pragma unroll
      for (int nt = 0; nt < 4; nt++)
        acc[mt][nt] = __builtin_amdgcn_mfma_f32_16x16x32_bf16(a[mt], b[nt], acc[mt][nt], 0, 0, 0);
    __syncthreads();
  }
#pragma unroll
  for (int mt = 0; mt < 4; mt++)
#pragma unroll
    for (int nt = 0; nt < 4; nt++)
#pragma unroll
      for (int r = 0; r < 4; r++) {
        int row = m0 + wm + mt * 16 + quad * 4 + r;
        int col = n0 + wn + nt * 16 + l16;
        if (OUTF32)
          ((float*)Cv)[(size_t)row * N + col] = acc[mt][nt][r];
        else
          ((u16*)Cv)[(size_t)row * N + col] = f2bf(acc[mt][nt][r]);
      }
}

// ---------------- RoPE in place on QKV buffer (bf16), Q + K heads only ----------------
__global__ void rope_k(u16* __restrict__ qkv, const int* __restrict__ pos) {
  int idx = blockIdx.x * 256 + threadIdx.x;
  int i = idx & 63;
  int hh = (idx >> 6) % 20;
  int row = idx / (64 * 20);
  int s = row & (S_LEN - 1);
  float p = (float)pos[s];
  float freq = __expf(-(float)i * 0.015625f * 9.210340371976184f);
  float ang = p * freq;
  float c = cosf(ang), sn = sinf(ang);
  int col = (hh < 16) ? hh * 128 : 2048 + (hh - 16) * 128;
  size_t base = (size_t)row * NQKV + col + i;
  float t1 = bf2f(qkv[base]), t2 = bf2f(qkv[base + 64]);
  qkv[base] = f2bf(t1 * c - t2 * sn);
  qkv[base + 64] = f2bf(t2 * c + t1 * sn);
}

// ---------------- Flash attention, causal GQA ----------------
// Pair-balanced sequential (block p: q-tile 31-p then p; 33 k-iters/block).
// K/V staged via global_load_lds DMA only (DMA dest must be linear:
// base + lane*16B). This version adds XOR bank-deconflict swizzle:
//   K LDS layout: [64 keys][128 d]  (256B rows, 16x 16B slots/row)
//   V LDS layout: [128 d ][64 keys] (128B rows,  8x 16B slots/row)
//   slot' = slot ^ (row & 7), applied on the *global source* address at
//   DMA time (rule: linear dest + inverse-swizzled source) and on the
//   ds_read side. Old 64B-row layouts were an 8-way read conflict
//   (2.94x LDS cost, 9.2M conflict cycles/dispatch = ~21% of CU time);
//   post-swizzle each quarter-wave hits 8 distinct 4-bank groups 2-way
//   (free per m136). Fragment->MFMA mapping is unchanged (bit-identical).
// Softmax: no max-tracking (m=0 safe, |score| <~ 20); row-sum l via two
// ones-column MFMAs; DMA double-buffer, ONE barrier per iter.
// LDS 73 KB -> 2 blocks/CU (grid is 512 = 2/CU anyway).
#define PL_LD 72
__global__ __launch_bounds__(256) void attn_k(const u16* __restrict__ qkv,
                                              const u16* __restrict__ vt,
                                              u16* __restrict__ ctx) {
  __shared__ u16 Kl[2][64 * 128];      // 2 x 16384 B, [key][d] swizzled
  __shared__ u16 Vl[2][128 * 64];      // 2 x 16384 B, [d][key] swizzled
  __shared__ u16 Pl[4][16 * PL_LD];    // 9216 B   (total 74752 B)
  const int p = blockIdx.x;
  const int h = blockIdx.y, bb = blockIdx.z;
  const int kvh = h >> 2;
  const int t = threadIdx.x, w = t >> 6, lane = t & 63;
  const int quad = lane >> 4, l16 = lane & 15;
  const int sx = l16 & 7;              // read-side swizzle key (row&7 == l16&7 here)
  // DMA staging decomposition (chunk = w*256 + ii*64 + lane, 16B chunks):
  //   K: key = w*16 + ii*4 + (lane>>4), slot = lane&15
  //   V: d   = w*32 + ii*8 + (lane>>3), slot = lane&7
  const int kkey0 = w * 16 + (lane >> 4);
  const int kslot = lane & 15;
  const int vd0 = w * 32 + (lane >> 3);
  const int vslot = lane & 7;
  const size_t rowbase = (size_t)bb * S_LEN;
  const u16* Kg0 = qkv + rowbase * NQKV + 2048 + kvh * 128;
  const u16* Vg0 = vt + (size_t)(bb * 4 + kvh) * 128 * 2048;
  const float c2 = 0.12751744f;  // (1/sqrt(128)) * log2(e)
  short8 onesf = {16256, 16256, 16256, 16256, 16256, 16256, 16256, 16256};  // bf16 1.0 x8

  for (int phase = 0; phase < 2; phase++) {
    const int qt = phase ? p : 31 - p;  // q-tile index; qt+1 k-iters
    const int rw = qt * 64 + w * 16;    // this wave's first q-row

    short8 qf[4];
#pragma unroll
    for (int ks = 0; ks < 4; ks++)
      qf[ks] = *(const short8*)(qkv + (rowbase + rw + l16) * NQKV + h * 128 + ks * 32 + quad * 8);

    floatx4 acc[8] = {};
    floatx4 accl = {0.f, 0.f, 0.f, 0.f};

    __syncthreads();  // protect buf0 from previous phase's reads
    // prologue DMA: kb=0 -> buffer 0
    {
      const u16* Kg = Kg0;
      const u16* Vg = Vg0;
#pragma unroll
      for (int ii = 0; ii < 4; ii++) {
        int key = kkey0 + ii * 4;
        gl2lds16(Kg + (size_t)key * NQKV + ((kslot ^ (key & 7)) * 8),
                 &Kl[0][0] + w * 2048 + ii * 512 + lane * 8);
      }
#pragma unroll
      for (int ii = 0; ii < 4; ii++) {
        int d = vd0 + ii * 8;
        gl2lds16(Vg + (size_t)d * 2048 + ((vslot ^ (d & 7)) * 8),
                 &Vl[0][0] + w * 2048 + ii * 512 + lane * 8);
      }
    }

    for (int kb = 0; kb <= qt; kb++) {
      const int cur = kb & 1;
      __syncthreads();  // drains DMA for buf[cur]; releases buf[cur^1] reads
      if (kb < qt) {    // prefetch kb+1 into the other buffer, overlapping compute
        const u16* Kg = Kg0 + (size_t)(kb + 1) * 64 * NQKV;
        const u16* Vg = Vg0 + (kb + 1) * 64;
        u16* KlN = &Kl[cur ^ 1][0];
        u16* VlN = &Vl[cur ^ 1][0];
#pragma unroll
        for (int ii = 0; ii < 4; ii++) {
          int key = kkey0 + ii * 4;
          gl2lds16(Kg + (size_t)key * NQKV + ((kslot ^ (key & 7)) * 8),
                   KlN + w * 2048 + ii * 512 + lane * 8);
        }
#pragma unroll
        for (int ii = 0; ii < 4; ii++) {
          int d = vd0 + ii * 8;
          gl2lds16(Vg + (size_t)d * 2048 + ((vslot ^ (d & 7)) * 8),
                   VlN + w * 2048 + ii * 512 + lane * 8);
        }
      }
      const u16* KlB = &Kl[cur][0];
      const u16* VlB = &Vl[cur][0];

      // ---- QK^T ----
      floatx4 sc[4];
#pragma unroll
      for (int nt = 0; nt < 4; nt++) {
        const u16* Krow = KlB + (nt * 16 + l16) * 128;
        short8 kf[4];
#pragma unroll
        for (int ks = 0; ks < 4; ks++)
          kf[ks] = *(const short8*)(Krow + (((ks * 4 + quad) ^ sx) * 8));
        floatx4 s = {0.f, 0.f, 0.f, 0.f};
#pragma unroll
        for (int ks = 0; ks < 4; ks++) s = __builtin_amdgcn_mfma_f32_16x16x32_bf16(qf[ks], kf[ks], s, 0, 0, 0);
        sc[nt] = s;
      }
      // ---- P = exp2(score * c2), causal mask on diagonal block, trunc-pack bf16 ----
      const bool diag = (kb == qt);
#pragma unroll
      for (int nt = 0; nt < 4; nt++)
#pragma unroll
        for (int r = 0; r < 4; r++) {
          float e = EXP2F(sc[nt][r] * c2);
          if (diag) {
            int keyg = kb * 64 + nt * 16 + l16;
            int rowg = rw + quad * 4 + r;
            if (keyg > rowg) e = 0.f;
          }
          Pl[w][(quad * 4 + r) * PL_LD + nt * 16 + l16] = (u16)(__float_as_uint(e) >> 16);
        }
      // ---- PV (+ ones-column row-sum into accl) ----
      short8 pf[2];
#pragma unroll
      for (int kh = 0; kh < 2; kh++)
        pf[kh] = *(const short8*)(&Pl[w][0] + l16 * PL_LD + kh * 32 + quad * 8);
      accl = __builtin_amdgcn_mfma_f32_16x16x32_bf16(pf[0], onesf, accl, 0, 0, 0);
      accl = __builtin_amdgcn_mfma_f32_16x16x32_bf16(pf[1], onesf, accl, 0, 0, 0);
#pragma unroll
      for (int nto = 0; nto < 8; nto++) {
        const u16* Vrow = VlB + (nto * 16 + l16) * 64;
        short8 vf0 = *(const short8*)(Vrow + ((quad ^ sx) * 8));
        short8 vf1 = *(const short8*)(Vrow + (((quad + 4) ^ sx) * 8));
        acc[nto] = __builtin_amdgcn_mfma_f32_16x16x32_bf16(pf[0], vf0, acc[nto], 0, 0, 0);
        acc[nto] = __builtin_amdgcn_mfma_f32_16x16x32_bf16(pf[1], vf1, acc[nto], 0, 0, 0);
      }
    }
    // ---- epilogue for this q-tile ----
#pragma unroll
    for (int r = 0; r < 4; r++) {
      float inv = 1.0f / accl[r];
      int rowg = rw + quad * 4 + r;
#pragma unroll
      for (int nto = 0; nto < 8; nto++) {
        int col = h * 128 + nto * 16 + l16;
        ctx[(rowbase + rowg) * 2048 + col] = f2bf(acc[nto][r] * inv);
      }
    }
  }
}

extern "C" void kernel_launch(void* const* d_in, const int* in_sizes, int n_in,
                              void* d_out, int out_size, void* d_ws, size_t ws_size,
                              hipStream_t stream) {
  const float* x  = (const float*)d_in[0];
  const int* pos  = (const int*)d_in[1];
  const float* Wq = (const float*)d_in[2];
  const float* Wk = (const float*)d_in[3];
  const float* Wv = (const float*)d_in[4];
  const float* Wo = (const float*)d_in[5];
  float* out = (float*)d_out;
  char* ws = (char*)d_ws;
  // ws layout (bf16): Xb[4096][2048] | WT[3072][2048] | WoT[2048][2048] | QKV[4096][3072] | CTX[4096][2048]
  u16* Xb  = (u16*)(ws);
  u16* WT  = (u16*)(ws + 16777216);
  u16* WoT = (u16*)(ws + 29360128);
  u16* QKV = (u16*)(ws + 37748736);
  u16* CTX = (u16*)(ws + 62914560);
  u16* VT  = Xb;  // [B*NKV][128][2048] bf16, 4 MB, reuses Xb after gemm1

  hipLaunchKernelGGL(cast_k, dim3(8192), dim3(256), 0, stream, x, Xb, 2097152);

  dim3 tb(32, 8);
  hipLaunchKernelGGL(transpose_k, dim3(64, 64), tb, 0, stream, Wq, WT, 2048, 2048);
  hipLaunchKernelGGL(transpose_k, dim3(16, 64), tb, 0, stream, Wk, WT + (size_t)2048 * 2048, 2048, 512);
  hipLaunchKernelGGL(transpose_k, dim3(16, 64), tb, 0, stream, Wv, WT + (size_t)2560 * 2048, 2048, 512);
  hipLaunchKernelGGL(transpose_k, dim3(64, 64), tb, 0, stream, Wo, WoT, 2048, 2048);

  hipLaunchKernelGGL(HIP_KERNEL_NAME(gemm_bt<false>), dim3(24, 32), dim3(256), 0, stream,
                     Xb, WT, (void*)QKV, 4096, 3072, 2048);
  hipLaunchKernelGGL(rope_k, dim3(20480), dim3(256), 0, stream, QKV, pos);
  hipLaunchKernelGGL(vtrans_k, dim3(64, 4, 8), tb, 0, stream, QKV, VT);
  hipLaunchKernelGGL(attn_k, dim3(16, 16, 2), dim3(256), 0, stream, QKV, VT, CTX);
  hipLaunchKernelGGL(HIP_KERNEL_NAME(gemm_bt<true>), dim3(16, 32), dim3(256), 0, stream,
                     CTX, WoT, (void*)out, 4096, 2048, 2048);
}